// Round 13
// baseline (9084.865 us; speedup 1.0000x reference)
//
#include <hip/hip_runtime.h>
#include <math.h>

// RNN with short-term plasticity: persistent cooperative kernel,
// 8 independent groups of 32 WGs (batch-partitioned).
//
// Round 13: SELF-VALIDATING DATA. Every cross-WG word is a u64
// {fp32 value, u32 seq} written by ONE 8B agent-scope store. Consumers
// poll the data itself (all 8 staged elements seq >= t+1), killing the
// separate flag round trip + stamp stores + drain-syncthreads that
// rounds 11/12 paid every step (their floor was 2 serial L3 trips).
// seq convention: A feeding GEMM step t carries seq t+1 (A0 -> 1,
// stored at step t for t+1 -> t+2). ZP z-partials likewise seq t+1,
// consumed at step t+1 (one step of slack -> poll non-blocking).
// Zeroed ws => seq 0 = invalid (poison-proof). No slot array, no grid
// barrier; 2 syncthreads/step; z-finalize overlaps the owner phase.
//
#define NH 1024
#define NB 32
#define NI 8
#define NO 8
#define TSTEPS 1000

#define NWG 256
#define BLK 512
#define NG 8          // independent groups
#define NM 32         // members (WGs) per group
#define GBATCH 4      // batches per group

// d_out float offsets (z, h, r, u concatenated flat)
#define OFF_Z 0
#define OFF_H (NB * TSTEPS * NO)            // 256000
#define OFF_R (OFF_H + NB * TSTEPS * NH)    // 33024000
#define OFF_U (OFF_R + NB * TSTEPS * NH)    // 65792000

#define APK_SZ (2 * NG * NH * GBATCH)       // u64 count = 65536 (512 KB)
#define ZPK_SZ (2 * NG * GBATCH * NO * NM)  // u64 count = 16384 (128 KB)

typedef unsigned long long u64;
typedef unsigned int u32;

__device__ __forceinline__ u64 aload64(const u64* p) {
    return __hip_atomic_load(p, __ATOMIC_RELAXED, __HIP_MEMORY_SCOPE_AGENT);
}
__device__ __forceinline__ void astore64(u64* p, u64 v) {
    __hip_atomic_store(p, v, __ATOMIC_RELAXED, __HIP_MEMORY_SCOPE_AGENT);
}
__device__ __forceinline__ u64 packvs(float f, u32 s) {
    return (u64)__builtin_bit_cast(u32, f) | ((u64)s << 32);
}
__device__ __forceinline__ float unpackf(u64 v) {
    return __builtin_bit_cast(float, (u32)v);
}

__global__ __launch_bounds__(BLK, 2) void rnn_stp_kernel(
    const float* __restrict__ x,     // [32][1000][8]
    const float* __restrict__ h0,    // [32][1024]
    const float* __restrict__ r0,    // [32][1024]
    const float* __restrict__ u0,    // [32][1024]
    const float* __restrict__ prel,  // [1024]
    const float* __restrict__ scal,  // [1024]
    const float* __restrict__ Wih,   // [1024][8]
    const float* __restrict__ Whh,   // [1024][1024]
    const float* __restrict__ Wmask, // [1024][1024]
    const float* __restrict__ Whz,   // [8][1024]
    float* __restrict__ out,
    float* __restrict__ ws)
{
    const int tid = threadIdx.x;
    const int g   = blockIdx.x;

    // G = g&7 -> group == XCD (locality heuristic only, never correctness).
    const int G = g & 7;
    const int m = g >> 3;

    u64* Apk = (u64*)ws;               // [2][NG][NH][GBATCH] {val, seq}
    u64* ZPk = Apk + APK_SZ;           // [2][NG][GBATCH][NO][NM] {val, seq}

    const int ib = 32 * m;             // first of 32 owned neurons

    // LDS: A-tile padded to 33 float4 per 32 rows (row j -> float4 j + j>>5)
    __shared__ float4 atile[NM * 33];          // 16.9 KB
    __shared__ float  red[8 * 16 * 9];         // 4.6 KB
    __shared__ float  wzlds[NM * 8];           // 1 KB: Whz[o][ib+on] -> [on*8+o]

    const int lane = tid & 63, wid = tid >> 6;

    // ---- stage Whz slice into LDS (one-time) ----
    if (tid < NM * 8)
        wzlds[(tid >> 3) * 8 + (tid & 7)] = Whz[(tid & 7) * NH + ib + (tid >> 3)];

    // ---- GEMM roles: ks = tid>>4 (j in [32ks,+32)), il = tid&15 ----
    const int ks = tid >> 4;
    const int il = tid & 15;

    // Masked weights (fully static indexing -> register-resident, rule #20)
    float w[2][32];
    #pragma unroll
    for (int nn = 0; nn < 2; ++nn) {
        const int row = 32 * m + il + 16 * nn;
        const float* wp = Whh   + row * NH + 32 * ks;
        const float* mp = Wmask + row * NH + 32 * ks;
        #pragma unroll
        for (int jj = 0; jj < 32; ++jj) w[nn][jj] = wp[jj] * mp[jj];
    }

    // ---- owner role: tid<128: local batch ob = tid>>5, neuron on = tid&31 ----
    const bool own = tid < 128;
    const int ob = tid >> 5;
    const int on = tid & 31;
    const int bglob = G * GBATCH + ob;
    const int oi = ib + on;
    float h = 0.f, r = 0.f, u = 0.f, htr = 0.f, p = 0.f, sc = 0.f;
    float wih[8];
    if (own) {
        h  = h0[bglob * NH + oi];
        r  = r0[bglob * NH + oi];
        u  = u0[bglob * NH + oi];
        p  = prel[oi];
        sc = scal[oi];
        #pragma unroll
        for (int k = 0; k < 8; ++k) wih[k] = Wih[oi * NI + k];
        htr = tanhf(h);
        astore64(&Apk[G * (NH * GBATCH) + oi * GBATCH + ob],
                 packvs(r * sc * htr, 1u));
    }

    // z-finalize mapping (wave 4): member m -> (bf, of)
    const int bf = m >> 3, of = m & 7;

    for (int t = 0; t < TSTEPS; ++t) {
        const int par = t & 1;

        // ---- x prefetch for owners (cached; issue before the poll) ----
        float4 xa = make_float4(0.f, 0.f, 0.f, 0.f), xb = xa;
        if (own) {
            const float4* xp = (const float4*)(x + (bglob * TSTEPS + t) * NI);
            xa = xp[0];
            xb = xp[1];
        }

        // ---- fused poll+stage: 8 self-validating u64 per thread ----
        const u64* Ap = Apk + par * (NG * NH * GBATCH) + G * (NH * GBATCH)
                        + tid * 8;
        const u32 need = (u32)(t + 1);
        u64 v0, v1, v2, v3, v4, v5, v6, v7;
        for (;;) {
            v0 = aload64(Ap + 0); v1 = aload64(Ap + 1);
            v2 = aload64(Ap + 2); v3 = aload64(Ap + 3);
            v4 = aload64(Ap + 4); v5 = aload64(Ap + 5);
            v6 = aload64(Ap + 6); v7 = aload64(Ap + 7);
            u32 s = (u32)(v0 >> 32);
            u32 s1 = (u32)(v1 >> 32); s = s1 < s ? s1 : s;
            u32 s2 = (u32)(v2 >> 32); s = s2 < s ? s2 : s;
            u32 s3 = (u32)(v3 >> 32); s = s3 < s ? s3 : s;
            u32 s4 = (u32)(v4 >> 32); s = s4 < s ? s4 : s;
            u32 s5 = (u32)(v5 >> 32); s = s5 < s ? s5 : s;
            u32 s6 = (u32)(v6 >> 32); s = s6 < s ? s6 : s;
            u32 s7 = (u32)(v7 >> 32); s = s7 < s ? s7 : s;
            if (s >= need) break;
            __builtin_amdgcn_s_sleep(1);
        }
        {
            const int r0i = tid * 2;           // rows r0i (even), r0i+1
            atile[r0i + (r0i >> 5)] =
                make_float4(unpackf(v0), unpackf(v1), unpackf(v2), unpackf(v3));
            atile[r0i + 1 + (r0i >> 5)] =
                make_float4(unpackf(v4), unpackf(v5), unpackf(v6), unpackf(v7));
        }
        __syncthreads();   // atile ready

        // ---- GEMM: 32 j x 2 rows x 4 b; FULL unroll, static indices ----
        float acc[2][4] = {{0.f,0.f,0.f,0.f},{0.f,0.f,0.f,0.f}};
        {
            const float4* at4 = atile + 33 * ks;
            #pragma unroll
            for (int jj = 0; jj < 32; ++jj) {
                float4 a = at4[jj];
                const float w0 = w[0][jj], w1 = w[1][jj];
                acc[0][0] = fmaf(a.x, w0, acc[0][0]);
                acc[0][1] = fmaf(a.y, w0, acc[0][1]);
                acc[0][2] = fmaf(a.z, w0, acc[0][2]);
                acc[0][3] = fmaf(a.w, w0, acc[0][3]);
                acc[1][0] = fmaf(a.x, w1, acc[1][0]);
                acc[1][1] = fmaf(a.y, w1, acc[1][1]);
                acc[1][2] = fmaf(a.z, w1, acc[1][2]);
                acc[1][3] = fmaf(a.w, w1, acc[1][3]);
            }
        }

        // ---- butterfly over ks low bits (lane bits 4,5) ----
        #pragma unroll
        for (int mm = 16; mm <= 32; mm <<= 1) {
            #pragma unroll
            for (int nn = 0; nn < 2; ++nn) {
                #pragma unroll
                for (int q = 0; q < 4; ++q)
                    acc[nn][q] += __shfl_xor(acc[nn][q], mm, 64);
            }
        }
        if (lane < 16) {
            float* rp = red + (wid * 16 + lane) * 9;
            rp[0] = acc[0][0]; rp[1] = acc[0][1];
            rp[2] = acc[0][2]; rp[3] = acc[0][3];
            rp[4] = acc[1][0]; rp[5] = acc[1][1];
            rp[6] = acc[1][2]; rp[7] = acc[1][3];
        }
        __syncthreads();   // red ready

        // ---- wave 4: finalize z[t-1] (overlaps the owner phase) ----
        if (t >= 1 && wid == 4) {
            float zv = 0.f;
            if (lane < NM) {
                const u64* zp = ZPk + (par ^ 1) * (NG * GBATCH * NO * NM)
                                + G * (GBATCH * NO * NM)
                                + bf * (NO * NM) + of * NM + lane;
                u64 vz;
                for (;;) {
                    vz = aload64(zp);
                    if ((u32)(vz >> 32) >= (u32)t) break;
                    __builtin_amdgcn_s_sleep(1);
                }
                zv = unpackf(vz);
            }
            zv += __shfl_xor(zv, 1, 64);
            zv += __shfl_xor(zv, 2, 64);
            zv += __shfl_xor(zv, 4, 64);
            zv += __shfl_xor(zv, 8, 64);
            zv += __shfl_xor(zv, 16, 64);
            if (lane == 0)
                out[OFF_Z + ((G * GBATCH + bf) * TSTEPS + (t - 1)) * NO + of] = zv;
        }

        // ---- owner: combine partials, update state, publish, write out ----
        if (own) {
            float rec = 0.f;
            #pragma unroll
            for (int wv = 0; wv < 8; ++wv)
                rec += red[(wv * 16 + (on & 15)) * 9 + (on >> 4) * 4 + ob];

            float xv = fmaf(xa.x, wih[0], fmaf(xa.y, wih[1],
                       fmaf(xa.z, wih[2], xa.w * wih[3])));
            xv = fmaf(xb.x, wih[4], fmaf(xb.y, wih[5],
                 fmaf(xb.z, wih[6], fmaf(xb.w, wih[7], xv))));

            float drive = 0.5f * (1.0f + htr);
            float rn = r + ((p - r) / 0.2f - 10.0f * r * drive) * 0.001f;
            float un = u + ((p - u) / 1.5f + 10.0f * (1.0f - u) * drive) * 0.001f;
            float hn = h + ((-h + xv + rec) / 0.01f) * 0.001f;
            float htn = tanhf(hn);

            // publish A for step t+1 FIRST (consumers' critical path)
            astore64(&Apk[(par ^ 1) * (NG * NH * GBATCH) + G * (NH * GBATCH)
                          + oi * GBATCH + ob],
                     packvs(rn * sc * htn, (u32)(t + 2)));

            // z partial for step t (seq t+1)
            float zp[8];
            #pragma unroll
            for (int o = 0; o < 8; ++o) zp[o] = htn * wzlds[on * 8 + o];
            #pragma unroll
            for (int mm = 1; mm <= 16; mm <<= 1) {
                #pragma unroll
                for (int o = 0; o < 8; ++o)
                    zp[o] += __shfl_xor(zp[o], mm, 64);
            }
            if (on == 0) {
                u64* zpp = ZPk + par * (NG * GBATCH * NO * NM)
                           + G * (GBATCH * NO * NM) + ob * (NO * NM) + m;
                #pragma unroll
                for (int o = 0; o < 8; ++o)
                    astore64(zpp + o * NM, packvs(zp[o], (u32)(t + 1)));
            }

            out[OFF_H + (bglob * TSTEPS + t) * NH + oi] = hn;
            out[OFF_R + (bglob * TSTEPS + t) * NH + oi] = rn;
            out[OFF_U + (bglob * TSTEPS + t) * NH + oi] = un;

            h = hn; r = rn; u = un; htr = htn;
        }
        // no end-of-loop barrier: next step's poll IS the synchronization
    }

    // ---- epilogue: finalize z[999] (ZPk[1], seq 1000) ----
    if (wid == 4) {
        float zv = 0.f;
        if (lane < NM) {
            const u64* zp = ZPk + 1 * (NG * GBATCH * NO * NM)
                            + G * (GBATCH * NO * NM)
                            + bf * (NO * NM) + of * NM + lane;
            u64 vz;
            for (;;) {
                vz = aload64(zp);
                if ((u32)(vz >> 32) >= (u32)TSTEPS) break;
                __builtin_amdgcn_s_sleep(1);
            }
            zv = unpackf(vz);
        }
        zv += __shfl_xor(zv, 1, 64);
        zv += __shfl_xor(zv, 2, 64);
        zv += __shfl_xor(zv, 4, 64);
        zv += __shfl_xor(zv, 8, 64);
        zv += __shfl_xor(zv, 16, 64);
        if (lane == 0)
            out[OFF_Z + ((G * GBATCH + bf) * TSTEPS + 999) * NO + of] = zv;
    }
}

extern "C" void kernel_launch(void* const* d_in, const int* in_sizes, int n_in,
                              void* d_out, int out_size, void* d_ws, size_t ws_size,
                              hipStream_t stream) {
    const float* x     = (const float*)d_in[0];
    const float* h0    = (const float*)d_in[1];
    const float* r0    = (const float*)d_in[2];
    const float* u0    = (const float*)d_in[3];
    const float* prel  = (const float*)d_in[4];
    const float* scal  = (const float*)d_in[5];
    const float* Wih   = (const float*)d_in[6];
    const float* Whh   = (const float*)d_in[7];
    const float* Wmask = (const float*)d_in[8];
    const float* Whz   = (const float*)d_in[9];
    float* out = (float*)d_out;
    float* ws  = (float*)d_ws;

    // Zero Apk+ZPk: seq=0 means "never valid", so the 0xAA poison (or a
    // previous replay's seqs) can never satisfy a poll.
    hipMemsetAsync(d_ws, 0, (size_t)(APK_SZ + ZPK_SZ) * sizeof(u64), stream);

    void* args[] = { &x, &h0, &r0, &u0, &prel, &scal,
                     &Wih, &Whh, &Wmask, &Whz, &out, &ws };
    hipLaunchCooperativeKernel((void*)rnn_stp_kernel, dim3(NWG), dim3(BLK),
                               args, 0, stream);
}

// Round 15
// 3815.474 us; speedup vs baseline: 2.3811x; 2.3811x over previous
//
#include <hip/hip_runtime.h>
#include <math.h>

// RNN with short-term plasticity: persistent kernel, batch-partitioned
// independent groups, per-group barrier.
//
// Round 15: round-14's co-residency idea with a SAFE launch. Round 14
// failed with the empty-kernel signature => hipLaunchCooperativeKernel
// silently rejected the 512-block grid. Here:
//  - Kernel A (512 WGs, 16 groups x 32 members, GBATCH=2, 2 WGs/CU so a
//    group's barrier stall hides under the co-resident group's compute)
//    is launched as a REGULAR kernel -- our sync is hand-rolled and only
//    needs co-residency -- and only if the occupancy query proves >=2
//    blocks/CU for the compiled binary (else it would deadlock).
//  - Kernel B = round-11 verbatim (proven 3.84 ms) as fallback.
//
#define NH 1024
#define NB 32
#define NI 8
#define NO 8
#define TSTEPS 1000

#define OFF_Z 0
#define OFF_H (NB * TSTEPS * NO)            // 256000
#define OFF_R (OFF_H + NB * TSTEPS * NH)    // 33024000
#define OFF_U (OFF_R + NB * TSTEPS * NH)    // 65792000

typedef unsigned long long u64;

__device__ __forceinline__ float2 aload2(const float* p) {
    u64 v = __hip_atomic_load((const u64*)p, __ATOMIC_RELAXED,
                              __HIP_MEMORY_SCOPE_AGENT);
    return __builtin_bit_cast(float2, v);
}
__device__ __forceinline__ float aload1(const float* p) {
    return __hip_atomic_load(p, __ATOMIC_RELAXED, __HIP_MEMORY_SCOPE_AGENT);
}
__device__ __forceinline__ void astore(float* p, float v) {
    __hip_atomic_store(p, v, __ATOMIC_RELAXED, __HIP_MEMORY_SCOPE_AGENT);
}

// ======================= Kernel A: 512 WGs, 2/CU =======================
#define A_NWG 512
#define A_NG 16
#define A_NM 32
#define A_GB 2
#define A_WS_A  16384                            // floats (slots = 512*128B)
#define A_WS_ZP (A_WS_A + 2 * A_NG * NH * A_GB)  // ZP[2][NG][GB][NO][NM]

__device__ __forceinline__ void groupbar_a(unsigned* slot, int G, int m,
                                           unsigned stamp) {
    __syncthreads();
    if (threadIdx.x == 0)
        __hip_atomic_store(&slot[(G * A_NM + m) * 32], stamp,
                           __ATOMIC_RELAXED, __HIP_MEMORY_SCOPE_AGENT);
    if (threadIdx.x < A_NM) {
        while (__hip_atomic_load(&slot[(G * A_NM + threadIdx.x) * 32],
                                 __ATOMIC_RELAXED, __HIP_MEMORY_SCOPE_AGENT)
               < stamp)
            __builtin_amdgcn_s_sleep(1);
    }
    __syncthreads();
}

__global__ __launch_bounds__(512, 2) void rnn_stp_kernel_a(
    const float* __restrict__ x,  const float* __restrict__ h0,
    const float* __restrict__ r0, const float* __restrict__ u0,
    const float* __restrict__ prel, const float* __restrict__ scal,
    const float* __restrict__ Wih,  const float* __restrict__ Whh,
    const float* __restrict__ Wmask, const float* __restrict__ Whz,
    float* __restrict__ out, float* __restrict__ ws)
{
    const int tid = threadIdx.x;
    const int g   = blockIdx.x;

    // Blocks g and g+256 share a CU under round-robin dispatch; groups G
    // and G+8 -> independent stalls. (Placement affects speed only.)
    const int G = g >> 5;
    const int m = g & 31;

    unsigned* slot = (unsigned*)ws;
    float* Abuf = ws + A_WS_A;   // [2][NG][NH][GB]
    float* ZP   = ws + A_WS_ZP;  // [2][NG][GB][NO][NM]

    const int ib = 32 * m;

    __shared__ float2 atile[NH + A_NM];        // padded: row j -> j + (j>>5)
    __shared__ float  red[8 * 16 * 5];
    __shared__ float  hbuf[A_GB][A_NM];

    const int lane = tid & 63, wid = tid >> 6;

    const int ks = tid >> 4;
    const int il = tid & 15;

    float w[2][32];
    #pragma unroll
    for (int nn = 0; nn < 2; ++nn) {
        const int row = 32 * m + il + 16 * nn;
        const float* wp = Whh   + row * NH + 32 * ks;
        const float* mp = Wmask + row * NH + 32 * ks;
        #pragma unroll
        for (int jj = 0; jj < 32; ++jj) w[nn][jj] = wp[jj] * mp[jj];
    }

    const bool own = tid < 64;
    const int ob = tid >> 5;
    const int on = tid & 31;
    const int bglob = G * A_GB + ob;
    const int oi = ib + on;
    float h = 0.f, r = 0.f, u = 0.f, htr = 0.f, p = 0.f, sc = 0.f;
    float wih[8];
    if (own) {
        h  = h0[bglob * NH + oi];
        r  = r0[bglob * NH + oi];
        u  = u0[bglob * NH + oi];
        p  = prel[oi];
        sc = scal[oi];
        #pragma unroll
        for (int k = 0; k < 8; ++k) wih[k] = Wih[oi * NI + k];
        htr = tanhf(h);
        astore(&Abuf[G * (NH * A_GB) + oi * A_GB + ob], r * sc * htr);
    }

    float wzv[4];
    #pragma unroll
    for (int k = 0; k < 4; ++k)
        wzv[k] = Whz[(lane >> 3) * NH + ib + (lane & 7) + 8 * k];
    const int bf = (m >> 3) & 1, of = m & 7;

    unsigned stamp = 1;
    groupbar_a(slot, G, m, stamp); ++stamp;

    for (int t = 0; t < TSTEPS; ++t) {
        const int par = t & 1;

        const float* Ag = Abuf + par * (A_NG * NH * A_GB) + G * (NH * A_GB);
        {
            float2 s0 = aload2(Ag + (2 * tid) * 2);
            float2 s1 = aload2(Ag + (2 * tid + 1) * 2);
            const int r0i = 2 * tid;
            atile[r0i + (r0i >> 5)]     = s0;
            atile[r0i + 1 + (r0i >> 5)] = s1;
        }

        float4 xa = make_float4(0.f, 0.f, 0.f, 0.f), xb = xa;
        if (own) {
            const float4* xp = (const float4*)(x + (bglob * TSTEPS + t) * NI);
            xa = xp[0];
            xb = xp[1];
        }
        __syncthreads();

        float acc[2][2] = {{0.f, 0.f}, {0.f, 0.f}};
        {
            const float2* at2 = atile + 33 * ks;
            #pragma unroll
            for (int jj = 0; jj < 32; ++jj) {
                float2 a = at2[jj];
                const float w0 = w[0][jj], w1 = w[1][jj];
                acc[0][0] = fmaf(a.x, w0, acc[0][0]);
                acc[0][1] = fmaf(a.y, w0, acc[0][1]);
                acc[1][0] = fmaf(a.x, w1, acc[1][0]);
                acc[1][1] = fmaf(a.y, w1, acc[1][1]);
            }
        }

        #pragma unroll
        for (int mm = 16; mm <= 32; mm <<= 1) {
            #pragma unroll
            for (int nn = 0; nn < 2; ++nn) {
                #pragma unroll
                for (int q = 0; q < 2; ++q)
                    acc[nn][q] += __shfl_xor(acc[nn][q], mm, 64);
            }
        }
        if (lane < 16) {
            float* rp = red + (wid * 16 + lane) * 5;
            rp[0] = acc[0][0]; rp[1] = acc[0][1];
            rp[2] = acc[1][0]; rp[3] = acc[1][1];
        }
        __syncthreads();

        if (own) {
            float rec = 0.f;
            #pragma unroll
            for (int wv = 0; wv < 8; ++wv)
                rec += red[(wv * 16 + (on & 15)) * 5 + (on >> 4) * 2 + ob];

            float xv = fmaf(xa.x, wih[0], fmaf(xa.y, wih[1],
                       fmaf(xa.z, wih[2], xa.w * wih[3])));
            xv = fmaf(xb.x, wih[4], fmaf(xb.y, wih[5],
                 fmaf(xb.z, wih[6], fmaf(xb.w, wih[7], xv))));

            float drive = 0.5f * (1.0f + htr);
            float rn = r + ((p - r) / 0.2f - 10.0f * r * drive) * 0.001f;
            float un = u + ((p - u) / 1.5f + 10.0f * (1.0f - u) * drive) * 0.001f;
            float hn = h + ((-h + xv + rec) / 0.01f) * 0.001f;
            float htn = tanhf(hn);

            out[OFF_H + (bglob * TSTEPS + t) * NH + oi] = hn;
            out[OFF_R + (bglob * TSTEPS + t) * NH + oi] = rn;
            out[OFF_U + (bglob * TSTEPS + t) * NH + oi] = un;

            astore(&Abuf[(par ^ 1) * (A_NG * NH * A_GB) + G * (NH * A_GB)
                         + oi * A_GB + ob], rn * sc * htn);
            hbuf[ob][on] = htn;

            h = hn; r = rn; u = un; htr = htn;
        }
        if (t >= 1 && wid == 4 && m < 16 && lane < A_NM) {
            float v = aload1(ZP + (par ^ 1) * (A_NG * A_GB * NO * A_NM)
                             + G * (A_GB * NO * A_NM)
                             + bf * (NO * A_NM) + of * A_NM + lane);
            v += __shfl_xor(v, 1, 64);
            v += __shfl_xor(v, 2, 64);
            v += __shfl_xor(v, 4, 64);
            v += __shfl_xor(v, 8, 64);
            v += __shfl_xor(v, 16, 64);
            if (lane == 0)
                out[OFF_Z + ((G * A_GB + bf) * TSTEPS + (t - 1)) * NO + of] = v;
        }
        __syncthreads();

        if (wid < A_GB) {
            const int o = lane >> 3, ns = lane & 7;
            float zp = 0.f;
            #pragma unroll
            for (int k = 0; k < 4; ++k)
                zp = fmaf(hbuf[wid][ns + 8 * k], wzv[k], zp);
            zp += __shfl_xor(zp, 1, 64);
            zp += __shfl_xor(zp, 2, 64);
            zp += __shfl_xor(zp, 4, 64);
            if (ns == 0)
                astore(&ZP[par * (A_NG * A_GB * NO * A_NM)
                           + G * (A_GB * NO * A_NM)
                           + wid * (NO * A_NM) + o * A_NM + m], zp);
        }

        groupbar_a(slot, G, m, stamp); ++stamp;
    }

    if (wid == 4 && m < 16) {
        float v = 0.f;
        if (lane < A_NM)
            v = aload1(ZP + 1 * (A_NG * A_GB * NO * A_NM)
                       + G * (A_GB * NO * A_NM)
                       + bf * (NO * A_NM) + of * A_NM + lane);
        v += __shfl_xor(v, 1, 64);
        v += __shfl_xor(v, 2, 64);
        v += __shfl_xor(v, 4, 64);
        v += __shfl_xor(v, 8, 64);
        v += __shfl_xor(v, 16, 64);
        if (lane == 0)
            out[OFF_Z + ((G * A_GB + bf) * TSTEPS + 999) * NO + of] = v;
    }
}

// ================= Kernel B: round-11 verbatim (256 WGs) =================
#define B_NWG 256
#define B_NG 8
#define B_NM 32
#define B_GB 4
#define B_WS_A  8192
#define B_WS_ZP (B_WS_A + 2 * B_NG * NH * B_GB)

__device__ __forceinline__ void groupbar_b(unsigned* slot, int G, int m,
                                           unsigned stamp) {
    __syncthreads();
    if (threadIdx.x == 0)
        __hip_atomic_store(&slot[(G * B_NM + m) * 32], stamp,
                           __ATOMIC_RELAXED, __HIP_MEMORY_SCOPE_AGENT);
    if (threadIdx.x < B_NM) {
        while (__hip_atomic_load(&slot[(G * B_NM + threadIdx.x) * 32],
                                 __ATOMIC_RELAXED, __HIP_MEMORY_SCOPE_AGENT)
               < stamp)
            __builtin_amdgcn_s_sleep(1);
    }
    __syncthreads();
}

__global__ __launch_bounds__(512, 2) void rnn_stp_kernel_b(
    const float* __restrict__ x,  const float* __restrict__ h0,
    const float* __restrict__ r0, const float* __restrict__ u0,
    const float* __restrict__ prel, const float* __restrict__ scal,
    const float* __restrict__ Wih,  const float* __restrict__ Whh,
    const float* __restrict__ Wmask, const float* __restrict__ Whz,
    float* __restrict__ out, float* __restrict__ ws)
{
    const int tid = threadIdx.x;
    const int g   = blockIdx.x;

    const int G = g & 7;
    const int m = g >> 3;

    unsigned* slot = (unsigned*)ws;
    float* Abuf = ws + B_WS_A;
    float* ZP   = ws + B_WS_ZP;

    const int ib = 32 * m;

    __shared__ float4 atile[B_NM * 33];
    __shared__ float  red[8 * 16 * 9];
    __shared__ float  hbuf[B_GB][B_NM];

    const int lane = tid & 63, wid = tid >> 6;

    const int ks = tid >> 4;
    const int il = tid & 15;

    float w[2][32];
    #pragma unroll
    for (int nn = 0; nn < 2; ++nn) {
        const int row = 32 * m + il + 16 * nn;
        const float* wp = Whh   + row * NH + 32 * ks;
        const float* mp = Wmask + row * NH + 32 * ks;
        #pragma unroll
        for (int jj = 0; jj < 32; ++jj) w[nn][jj] = wp[jj] * mp[jj];
    }

    const bool own = tid < 128;
    const int ob = tid >> 5;
    const int on = tid & 31;
    const int bglob = G * B_GB + ob;
    const int oi = ib + on;
    float h = 0.f, r = 0.f, u = 0.f, htr = 0.f, p = 0.f, sc = 0.f;
    float wih[8];
    if (own) {
        h  = h0[bglob * NH + oi];
        r  = r0[bglob * NH + oi];
        u  = u0[bglob * NH + oi];
        p  = prel[oi];
        sc = scal[oi];
        #pragma unroll
        for (int k = 0; k < 8; ++k) wih[k] = Wih[oi * NI + k];
        htr = tanhf(h);
        astore(&Abuf[G * (NH * B_GB) + oi * B_GB + ob], r * sc * htr);
    }

    float wzv[4];
    #pragma unroll
    for (int k = 0; k < 4; ++k)
        wzv[k] = Whz[(lane >> 3) * NH + ib + (lane & 7) + 8 * k];
    const int bf = m >> 3, of = m & 7;

    unsigned stamp = 1;
    groupbar_b(slot, G, m, stamp); ++stamp;

    for (int t = 0; t < TSTEPS; ++t) {
        const int par = t & 1;

        const float* Ag = Abuf + par * (B_NG * NH * B_GB) + G * (NH * B_GB);
        {
            float2 s0 = aload2(Ag + tid * 8 + 0);
            float2 s1 = aload2(Ag + tid * 8 + 2);
            float2 s2 = aload2(Ag + tid * 8 + 4);
            float2 s3 = aload2(Ag + tid * 8 + 6);
            const int r0i = tid * 2;
            atile[r0i + (r0i >> 5)]     = make_float4(s0.x, s0.y, s1.x, s1.y);
            atile[r0i + 1 + (r0i >> 5)] = make_float4(s2.x, s2.y, s3.x, s3.y);
        }

        float4 xa = make_float4(0.f, 0.f, 0.f, 0.f), xb = xa;
        if (own) {
            const float4* xp = (const float4*)(x + (bglob * TSTEPS + t) * NI);
            xa = xp[0];
            xb = xp[1];
        }
        __syncthreads();

        float acc[2][4] = {{0.f,0.f,0.f,0.f},{0.f,0.f,0.f,0.f}};
        {
            const float4* at4 = atile + 33 * ks;
            #pragma unroll
            for (int jj = 0; jj < 32; ++jj) {
                float4 a = at4[jj];
                const float w0 = w[0][jj], w1 = w[1][jj];
                acc[0][0] = fmaf(a.x, w0, acc[0][0]);
                acc[0][1] = fmaf(a.y, w0, acc[0][1]);
                acc[0][2] = fmaf(a.z, w0, acc[0][2]);
                acc[0][3] = fmaf(a.w, w0, acc[0][3]);
                acc[1][0] = fmaf(a.x, w1, acc[1][0]);
                acc[1][1] = fmaf(a.y, w1, acc[1][1]);
                acc[1][2] = fmaf(a.z, w1, acc[1][2]);
                acc[1][3] = fmaf(a.w, w1, acc[1][3]);
            }
        }

        #pragma unroll
        for (int mm = 16; mm <= 32; mm <<= 1) {
            #pragma unroll
            for (int nn = 0; nn < 2; ++nn) {
                #pragma unroll
                for (int q = 0; q < 4; ++q)
                    acc[nn][q] += __shfl_xor(acc[nn][q], mm, 64);
            }
        }
        if (lane < 16) {
            float* rp = red + (wid * 16 + lane) * 9;
            rp[0] = acc[0][0]; rp[1] = acc[0][1];
            rp[2] = acc[0][2]; rp[3] = acc[0][3];
            rp[4] = acc[1][0]; rp[5] = acc[1][1];
            rp[6] = acc[1][2]; rp[7] = acc[1][3];
        }
        __syncthreads();

        if (own) {
            float rec = 0.f;
            #pragma unroll
            for (int wv = 0; wv < 8; ++wv)
                rec += red[(wv * 16 + (on & 15)) * 9 + (on >> 4) * 4 + ob];

            float xv = fmaf(xa.x, wih[0], fmaf(xa.y, wih[1],
                       fmaf(xa.z, wih[2], xa.w * wih[3])));
            xv = fmaf(xb.x, wih[4], fmaf(xb.y, wih[5],
                 fmaf(xb.z, wih[6], fmaf(xb.w, wih[7], xv))));

            float drive = 0.5f * (1.0f + htr);
            float rn = r + ((p - r) / 0.2f - 10.0f * r * drive) * 0.001f;
            float un = u + ((p - u) / 1.5f + 10.0f * (1.0f - u) * drive) * 0.001f;
            float hn = h + ((-h + xv + rec) / 0.01f) * 0.001f;
            float htn = tanhf(hn);

            out[OFF_H + (bglob * TSTEPS + t) * NH + oi] = hn;
            out[OFF_R + (bglob * TSTEPS + t) * NH + oi] = rn;
            out[OFF_U + (bglob * TSTEPS + t) * NH + oi] = un;

            astore(&Abuf[(par ^ 1) * (B_NG * NH * B_GB) + G * (NH * B_GB)
                         + oi * B_GB + ob], rn * sc * htn);
            hbuf[ob][on] = htn;

            h = hn; r = rn; u = un; htr = htn;
        }
        __syncthreads();

        if (wid < 4) {
            const int o = lane >> 3, ns = lane & 7;
            float zp = 0.f;
            #pragma unroll
            for (int k = 0; k < 4; ++k)
                zp = fmaf(hbuf[wid][ns + 8 * k], wzv[k], zp);
            zp += __shfl_xor(zp, 1, 64);
            zp += __shfl_xor(zp, 2, 64);
            zp += __shfl_xor(zp, 4, 64);
            if (ns == 0)
                astore(&ZP[par * (B_NG * B_GB * NO * B_NM)
                           + G * (B_GB * NO * B_NM)
                           + wid * (NO * B_NM) + o * B_NM + m], zp);
        }
        if (t >= 1 && wid == 4 && lane < B_NM) {
            float v = aload1(ZP + (par ^ 1) * (B_NG * B_GB * NO * B_NM)
                             + G * (B_GB * NO * B_NM)
                             + bf * (NO * B_NM) + of * B_NM + lane);
            v += __shfl_xor(v, 1, 64);
            v += __shfl_xor(v, 2, 64);
            v += __shfl_xor(v, 4, 64);
            v += __shfl_xor(v, 8, 64);
            v += __shfl_xor(v, 16, 64);
            if (lane == 0)
                out[OFF_Z + ((G * B_GB + bf) * TSTEPS + (t - 1)) * NO + of] = v;
        }

        groupbar_b(slot, G, m, stamp); ++stamp;
    }

    if (wid == 4 && lane < B_NM) {
        float v = aload1(ZP + 1 * (B_NG * B_GB * NO * B_NM)
                         + G * (B_GB * NO * B_NM)
                         + bf * (NO * B_NM) + of * B_NM + lane);
        v += __shfl_xor(v, 1, 64);
        v += __shfl_xor(v, 2, 64);
        v += __shfl_xor(v, 4, 64);
        v += __shfl_xor(v, 8, 64);
        v += __shfl_xor(v, 16, 64);
        if (lane == 0)
            out[OFF_Z + ((G * B_GB + bf) * TSTEPS + 999) * NO + of] = v;
    }
}

extern "C" void kernel_launch(void* const* d_in, const int* in_sizes, int n_in,
                              void* d_out, int out_size, void* d_ws, size_t ws_size,
                              hipStream_t stream) {
    const float* x     = (const float*)d_in[0];
    const float* h0    = (const float*)d_in[1];
    const float* r0    = (const float*)d_in[2];
    const float* u0    = (const float*)d_in[3];
    const float* prel  = (const float*)d_in[4];
    const float* scal  = (const float*)d_in[5];
    const float* Wih   = (const float*)d_in[6];
    const float* Whh   = (const float*)d_in[7];
    const float* Wmask = (const float*)d_in[8];
    const float* Whz   = (const float*)d_in[9];
    float* out = (float*)d_out;
    float* ws  = (float*)d_ws;

    // Deterministic path choice: take the 512-WG kernel only if the
    // compiled binary provably fits 2 blocks/CU (else it would deadlock
    // under a regular launch, and cooperative launch rejects >256).
    int occ = 0;
    hipError_t e = hipOccupancyMaxActiveBlocksPerMultiprocessor(
        &occ, (const void*)rnn_stp_kernel_a, 512, 0);
    const bool useA = (e == hipSuccess) && (occ >= 2);

    if (useA) {
        hipMemsetAsync(d_ws, 0, A_NWG * 128, stream);
        rnn_stp_kernel_a<<<dim3(A_NWG), dim3(512), 0, stream>>>(
            x, h0, r0, u0, prel, scal, Wih, Whh, Wmask, Whz, out, ws);
    } else {
        hipMemsetAsync(d_ws, 0, B_NWG * 128, stream);
        void* args[] = { &x, &h0, &r0, &u0, &prel, &scal,
                         &Wih, &Whh, &Wmask, &Whz, &out, &ws };
        hipLaunchCooperativeKernel((void*)rnn_stp_kernel_b, dim3(B_NWG),
                                   dim3(512), args, 0, stream);
    }
}